// Round 10
// baseline (122.693 us; speedup 1.0000x reference)
//
#include <hip/hip_runtime.h>

#define BATCH 524288

typedef __bf16 bf16x8 __attribute__((ext_vector_type(8)));
typedef __bf16 bf16x2 __attribute__((ext_vector_type(2)));
typedef float f32x4 __attribute__((ext_vector_type(4)));
typedef float f32x8 __attribute__((ext_vector_type(8)));
typedef float f32x2 __attribute__((ext_vector_type(2)));
typedef int   i32x4 __attribute__((ext_vector_type(4)));

// LDS layout (all fragment reads are lane-consecutive 16B chunks = conflict-free):
//   sA2  @     0: 16384 B  A2, chunk(kk, lane)=kk*1024+lane*16
//   sW1f @ 16384:  4096 B  W1 frags; +32 B zero chunk @ 20480
//   sW2f @ 20512:  8192 B  W2 permuted frags (v9-verified)
//   sB2  @ 28704:   128 B  b2 f32 (f32x4 broadcast reads, seeds G2 C-operand regs)
//   sXT  @ 28832:    64 B  x_target f32
//   sB1  @ 28896:   512 B  b1 f32 (read once into b1v[8] regs)
//   hcw  @ 29408 + wave*2560 + t01*1280: 16 rows x 40 bf16
//
// v16: DS-pipe diet (v15 post-mortem: DS-latency hoist null -> latency already
//      TLP-hidden; revised model: ~228 DS instrs/wave on one shared LDS pipe/CU
//      ~= the 43us runtime -> DS THROUGHPUT bound). All p-invariant LDS data
//      hoisted to registers under __launch_bounds__(512,2) (budget 128):
//      w1f[8]+w2f[8] frags (+64 VGPR, -16 b128/p), b1 back to 8 scalar regs +
//      v_add (-8 b128/p for +32 VALU adds), xtv hoisted. G3 reverted to v14
//      interleaved (sel[16] hoist was null + pressure). DS/wave ~228 -> ~180.
//      Occupancy cap 16 waves/CU (2 blocks) - empirically free (v10 ~= v13).
#define SW1 16384
#define SZC 20480
#define SW2 20512
#define SB2 28704
#define SXT 28832
#define SB1 28896
#define SHC 29408
#define NWAVES 8
#define SMEM_BYTES (29408 + NWAVES * 2560)   // 49888 B (<64K, no attr needed)

__device__ __forceinline__ f32x8 load8(const float* __restrict__ p) {
    float4 a = *(const float4*)p;
    float4 b = *(const float4*)(p + 4);
    f32x8 v = {a.x, a.y, a.z, a.w, b.x, b.y, b.z, b.w};
    return v;
}

__device__ __forceinline__ int pack2bf(float a, float b) {
    f32x2 v = {a, b};
    bf16x2 p = __builtin_convertvector(v, bf16x2);
    return __builtin_bit_cast(int, p);
}

__global__ __launch_bounds__(512, 2) void andp_v16(
    const float* __restrict__ x_cur,
    const float* __restrict__ W1,
    const float* __restrict__ b1,
    const float* __restrict__ W2,
    const float* __restrict__ b2,
    const float* __restrict__ Bm,
    const float* __restrict__ Cm,
    const float* __restrict__ x_t,
    float* __restrict__ out)
{
    extern __shared__ char smem[];
    int* sA2i = (int*)smem;
    int* sW1i = (int*)(smem + SW1);
    int* sW2i = (int*)(smem + SW2);
    const int tid = threadIdx.x;

    // ---- stage A2 = Bm + Cm, lane-consecutive chunk order ----
#pragma unroll
    for (int i = 0; i < 8; ++i) {
        int o2 = tid + i * 512;                 // b32 index 0..4095
        int o  = o2 * 2;                        // elem (j even)
        int kk = o >> 9, qp = (o >> 7) & 3, k = (o >> 3) & 15, j = o & 7;
        int n = 2 * kk + (qp >> 1), d = (qp & 1) * 8 + j;
        int src = n * 256 + k * 16 + d;
        float2 bv = *(const float2*)(Bm + src);
        float2 cv = *(const float2*)(Cm + src);
        sA2i[o2] = pack2bf(bv.x + cv.x, bv.y + cv.y);
    }
    // ---- stage W1 frags, lane-consecutive chunk order; + zero chunk ----
#pragma unroll
    for (int i = 0; i < 2; ++i) {
        int o2 = tid + i * 512;                 // b32 index 0..1023
        int o  = o2 * 2;                        // elem (j even)
        int t = o >> 8, qq = (o >> 7) & 1, cc = (o >> 3) & 15, j = o & 7;
        int src = (t * 16 + cc) * 16 + qq * 8 + j;
        float2 v = *(const float2*)(W1 + src);
        sW1i[o2] = pack2bf(v.x, v.y);
    }
    if (tid < 8) ((int*)(smem + SZC))[tid] = 0;
    // ---- stage W2 in permuted frag order (v9-verified) ----
#pragma unroll
    for (int i = 0; i < 4; ++i) {
        int o2 = tid + i * 512;                 // b32 index 0..2047
        int chunk = o2 >> 8, rem = o2 & 255;
        int ln = rem >> 2, j2 = rem & 3;
        int qq = ln >> 4, cc = ln & 15;
        int t2 = chunk >> 2, s = chunk & 3;
        int src = (t2 * 16 + cc) * 128 + s * 32 + 4 * qq + j2;
        sW2i[o2] = pack2bf(W2[src], W2[src + 16]);
    }
    if (tid < 32) ((float*)(smem + SB2))[tid] = b2[tid];
    if (tid < 16) ((float*)(smem + SXT))[tid] = x_t[tid];
    if (tid < 128) ((float*)(smem + SB1))[tid] = b1[tid];

    const int wave = tid >> 6, lane = tid & 63;
    const int c = lane & 15, q = lane >> 4;
    const int qh = q >> 1;                       // n parity for G3
    const int hh = (q & 1) * 8;                  // d-half this lane owns
    const int c4 = c * 4;

    const char* sW1f = smem + SW1;
    const int w1base = (q < 2) ? ((q * 16 + c) * 16) : (SZC - SW1);
    const int w1step = (q < 2) ? 512 : 0;
    const char* sW2f = smem + SW2 + lane * 16;   // + chunk*1024
    __bf16* hcw0 = (__bf16*)(smem + SHC + wave * 2560);
    __bf16* hcw1 = hcw0 + 640;
    const float* sB2f = (const float*)(smem + SB2);
    const float* sXTf = (const float*)(smem + SXT);
    const float* sB1f = (const float*)(smem + SB1);

    __syncthreads();

    // ---- hoist ALL p-invariant LDS data into registers (read once/block) ----
    bf16x8 w1f[8], w2f[8];
#pragma unroll
    for (int i = 0; i < 8; ++i) {
        w1f[i] = *(const bf16x8*)(sW1f + w1base + i * w1step);
        w2f[i] = *(const bf16x8*)(sW2f + i * 1024);
    }
    float b1v[8];
#pragma unroll
    for (int t = 0; t < 8; ++t) b1v[t] = sB1f[t * 16 + c];
    f32x8 xtv;
    {
        f32x4 xta = *(const f32x4*)(sXTf + hh);
        f32x4 xtb = *(const f32x4*)(sXTf + hh + 4);
        xtv = (f32x8){xta[0], xta[1], xta[2], xta[3], xtb[0], xtb[1], xtb[2], xtb[3]};
    }
    // p-invariant G2 bias seeds (layout matches D: reg r <-> n = half*16 + q*4+r)
    const f32x4 bq0 = *(const f32x4*)(sB2f + q * 4);
    const f32x4 bq1 = *(const f32x4*)(sB2f + 16 + q * 4);

    const int blk_row = blockIdx.x * 512 + wave * 64;
    const f32x4 z4 = {0.f, 0.f, 0.f, 0.f};

    // ---- p=0 x load (prefetched inside loop thereafter) ----
    bf16x8 af[2];
#pragma unroll
    for (int t01 = 0; t01 < 2; ++t01) {
        f32x8 xv = load8(x_cur + (size_t)(blk_row + t01 * 16 + c) * 16 + hh);
        af[t01] = __builtin_convertvector(xv, bf16x8);
    }

#pragma unroll 1
    for (int p = 0; p < 2; ++p) {
        const int r0 = blk_row + p * 32;

        // ---- fused G1/G2, t01-interleaved; G2 bias via C-seed regs ----
        f32x4 acc2[2][2];
        acc2[0][0] = bq0; acc2[0][1] = bq1; acc2[1][0] = bq0; acc2[1][1] = bq1;
#pragma unroll
        for (int s = 0; s < 4; ++s) {
            float b1a = b1v[2 * s];
            float b1b = b1v[2 * s + 1];
#pragma unroll
            for (int t01 = 0; t01 < 2; ++t01) {
                __bf16* hcw = t01 ? hcw1 : hcw0;
                f32x4 a1a = __builtin_amdgcn_mfma_f32_16x16x32_bf16(af[t01], w1f[2 * s], z4, 0, 0, 0);
                f32x4 a1b = __builtin_amdgcn_mfma_f32_16x16x32_bf16(af[t01], w1f[2 * s + 1], z4, 0, 0, 0);
#pragma unroll
                for (int r = 0; r < 4; ++r) {
                    float va = fmaxf(a1a[r] + b1a, 0.f);
                    float vb = fmaxf(a1b[r] + b1b, 0.f);
                    *(int*)(hcw + (q * 4 + r) * 40 + 2 * c) = pack2bf(va, vb);
                }
            }
#pragma unroll
            for (int t01 = 0; t01 < 2; ++t01) {
                __bf16* hcw = t01 ? hcw1 : hcw0;
                bf16x8 hb = *(const bf16x8*)(hcw + c * 40 + q * 8);
                acc2[t01][0] = __builtin_amdgcn_mfma_f32_16x16x32_bf16(w2f[s], hb, acc2[t01][0], 0, 0, 0);
                acc2[t01][1] = __builtin_amdgcn_mfma_f32_16x16x32_bf16(w2f[4 + s], hb, acc2[t01][1], 0, 0, 0);
            }
        }

        // ---- prefetch next-p x (issued here so HBM latency hides under SM+G3) ----
        bf16x8 afn0 = af[0], afn1 = af[1];
        if (p == 0) {
            f32x8 xv0 = load8(x_cur + (size_t)(blk_row + 32 + c) * 16 + hh);
            f32x8 xv1 = load8(x_cur + (size_t)(blk_row + 48 + c) * 16 + hh);
            afn0 = __builtin_convertvector(xv0, bf16x8);
            afn1 = __builtin_convertvector(xv1, bf16x8);
        }

        // ---- softmax, both t01 then single-pack ----
        int wq[8];
        {
            float e0[8], e1[8], sum0 = 0.f, sum1 = 0.f;
#pragma unroll
            for (int r = 0; r < 4; ++r) {
                e0[r]     = __expf(acc2[0][0][r]);
                e0[4 + r] = __expf(acc2[0][1][r]);
                e1[r]     = __expf(acc2[1][0][r]);
                e1[4 + r] = __expf(acc2[1][1][r]);
                sum0 += e0[r] + e0[4 + r];
                sum1 += e1[r] + e1[4 + r];
            }
            sum0 += __shfl_xor(sum0, 16, 64);
            sum0 += __shfl_xor(sum0, 32, 64);
            sum1 += __shfl_xor(sum1, 16, 64);
            sum1 += __shfl_xor(sum1, 32, 64);
            float inv0 = 1.0f / sum0;
            float inv1 = 1.0f / sum1;
#pragma unroll
            for (int i = 0; i < 8; ++i)
                wq[i] = pack2bf(e0[i] * inv0, e1[i] * inv1);
        }

        // ---- reconstruct dif from af (bf16 x) + hoisted x_target ----
        f32x8 dif[2];
        dif[0] = xtv - __builtin_convertvector(af[0], f32x8);
        dif[1] = xtv - __builtin_convertvector(af[1], f32x8);

        // ---- G3 (v14 interleaved form; f32x2-structured scaling) ----
        f32x4 acc3[2];
        acc3[0] = z4; acc3[1] = z4;
#pragma unroll
        for (int kk = 0; kk < 16; ++kk) {
            const int lo = (kk >> 3) * 4 + 2 * (kk & 1);
            const int bpi = c4 + ((kk >> 1) & 3) * 64;
            int bpA = __builtin_amdgcn_ds_bpermute(bpi, wq[lo]);      // n = 2kk
            int bpB = __builtin_amdgcn_ds_bpermute(bpi, wq[lo + 1]);  // n = 2kk+1
            int sel = qh ? bpB : bpA;                                  // n = 2kk+qh
            float w0 = __builtin_bit_cast(float, (unsigned)sel << 16);
            float w1 = __builtin_bit_cast(float, (unsigned)sel & 0xffff0000u);
            f32x2 w0p = {w0, w0}, w1p = {w1, w1};
            i32x4 g0i, g1i;
#pragma unroll
            for (int jj = 0; jj < 4; ++jj) {
                f32x2 d0 = {dif[0][2 * jj], dif[0][2 * jj + 1]};
                f32x2 d1 = {dif[1][2 * jj], dif[1][2 * jj + 1]};
                f32x2 p0 = d0 * w0p;
                f32x2 p1 = d1 * w1p;
                g0i[jj] = pack2bf(p0[0], p0[1]);
                g1i[jj] = pack2bf(p1[0], p1[1]);
            }
            bf16x8 a2f = *(const bf16x8*)(smem + kk * 1024 + lane * 16);
            bf16x8 g0 = __builtin_bit_cast(bf16x8, g0i);
            bf16x8 g1 = __builtin_bit_cast(bf16x8, g1i);
            acc3[0] = __builtin_amdgcn_mfma_f32_16x16x32_bf16(a2f, g0, acc3[0], 0, 0, 0);
            acc3[1] = __builtin_amdgcn_mfma_f32_16x16x32_bf16(a2f, g1, acc3[1], 0, 0, 0);
        }

        // ---- store: D[m=k_out=q*4+r][n=row=c] -> float4 per tile ----
#pragma unroll
        for (int t01 = 0; t01 < 2; ++t01) {
            float4 st = make_float4(acc3[t01][0], acc3[t01][1], acc3[t01][2], acc3[t01][3]);
            *(float4*)(out + (size_t)(r0 + t01 * 16 + c) * 16 + q * 4) = st;
        }

        af[0] = afn0;
        af[1] = afn1;
    }
}

extern "C" void kernel_launch(void* const* d_in, const int* in_sizes, int n_in,
                              void* d_out, int out_size, void* d_ws, size_t ws_size,
                              hipStream_t stream) {
    const float* x_cur = (const float*)d_in[0];
    const float* W1    = (const float*)d_in[1];
    const float* b1    = (const float*)d_in[2];
    const float* W2    = (const float*)d_in[3];
    const float* b2    = (const float*)d_in[4];
    const float* Bm    = (const float*)d_in[5];
    const float* Cm    = (const float*)d_in[6];
    const float* x_t   = (const float*)d_in[7];
    float* out = (float*)d_out;

    const int blocks = BATCH / 512;   // 1024 blocks x 512 rows
    andp_v16<<<blocks, 512, SMEM_BYTES, stream>>>(
        x_cur, W1, b1, W2, b2, Bm, Cm, x_t, out);
}

// Round 17
// 119.340 us; speedup vs baseline: 1.0281x; 1.0281x over previous
//
#include <hip/hip_runtime.h>

#define BATCH 524288

typedef __bf16 bf16x8 __attribute__((ext_vector_type(8)));
typedef __bf16 bf16x2 __attribute__((ext_vector_type(2)));
typedef float f32x4 __attribute__((ext_vector_type(4)));
typedef float f32x8 __attribute__((ext_vector_type(8)));
typedef float f32x2 __attribute__((ext_vector_type(2)));

// LDS layout (all fragment reads are lane-consecutive 16B chunks = conflict-free):
//   sA2  @     0: 16384 B  A2, chunk(kk, lane)=kk*1024+lane*16; lane(c,q) elems j ->
//                          A[n=2kk+(q>>1)][k_out=c][d=(q&1)*8+j]  (n-parity = K>>4)
//   sW1f @ 16384:  4096 B  W1 frags; +32 B zero chunk @ 20480
//   sW2f @ 20512:  8192 B  W2 permuted frags (v9-verified)
//   sB2  @ 28704:   128 B  b2 f32 (f32x4 broadcast reads, seeds G2 C-operand)
//   sXT  @ 28832:    64 B  x_target f32
//   sB1r @ 28896:  2048 B  b1 replicated x4 (f32x4 splat reads, seeds G1 C-operand)
//   hcw  @ 30944 + wave*2560 + t01*1280: 16 rows x 40 bf16
//
// v18: corrected output-scaled G3 (v17 post-mortem: single mfma(a2f,difb) sums BOTH
//      systems 2kk/2kk+1 -- parity lives in K -- so one output gate can't un-mix;
//      absmax 3.3). Fix: parity-split MFMAs. difbE = (q<2 ? difb : 0) makes only
//      K<16 (n=2kk) contribute; difbO the complement. Then
//        acc3[t01] += wA[t01]*prE[t01] + wB[t01]*prO[t01]
//      with the same v8-verified bpermute gates as 4 f32 bit-extracted scalars.
//      G3 MFMAs depend ONLY on the a2f LDS read (pure LDS->MFMA stream); the
//      bpermute+fma gate chain is independent; 16 cvt_pk/kk removed (8 once/p).
//      MFMA/p: 32->64 (idle pipe, 15% util). Numerics: fewer roundings than v14.
//      Base = v14 ((512,3), C-seed biases, x-prefetch) + v15 single-pack softmax.
#define SW1 16384
#define SZC 20480
#define SW2 20512
#define SB2 28704
#define SXT 28832
#define SB1 28896
#define SHC 30944
#define NWAVES 8
#define SMEM_BYTES (30944 + NWAVES * 2560)   // 51424 B -> 3 blocks/CU (154.3/160 KB)

__device__ __forceinline__ f32x8 load8(const float* __restrict__ p) {
    float4 a = *(const float4*)p;
    float4 b = *(const float4*)(p + 4);
    f32x8 v = {a.x, a.y, a.z, a.w, b.x, b.y, b.z, b.w};
    return v;
}

__device__ __forceinline__ int pack2bf(float a, float b) {
    f32x2 v = {a, b};
    bf16x2 p = __builtin_convertvector(v, bf16x2);
    return __builtin_bit_cast(int, p);
}

__global__ __launch_bounds__(512, 3) void andp_v18(
    const float* __restrict__ x_cur,
    const float* __restrict__ W1,
    const float* __restrict__ b1,
    const float* __restrict__ W2,
    const float* __restrict__ b2,
    const float* __restrict__ Bm,
    const float* __restrict__ Cm,
    const float* __restrict__ x_t,
    float* __restrict__ out)
{
    extern __shared__ char smem[];
    int* sA2i = (int*)smem;
    int* sW1i = (int*)(smem + SW1);
    int* sW2i = (int*)(smem + SW2);
    const int tid = threadIdx.x;

    // ---- stage A2 = Bm + Cm, lane-consecutive chunk order ----
#pragma unroll
    for (int i = 0; i < 8; ++i) {
        int o2 = tid + i * 512;                 // b32 index 0..4095
        int o  = o2 * 2;                        // elem (j even)
        int kk = o >> 9, qp = (o >> 7) & 3, k = (o >> 3) & 15, j = o & 7;
        int n = 2 * kk + (qp >> 1), d = (qp & 1) * 8 + j;
        int src = n * 256 + k * 16 + d;
        float2 bv = *(const float2*)(Bm + src);
        float2 cv = *(const float2*)(Cm + src);
        sA2i[o2] = pack2bf(bv.x + cv.x, bv.y + cv.y);
    }
    // ---- stage W1 frags, lane-consecutive chunk order; + zero chunk ----
#pragma unroll
    for (int i = 0; i < 2; ++i) {
        int o2 = tid + i * 512;                 // b32 index 0..1023
        int o  = o2 * 2;                        // elem (j even)
        int t = o >> 8, qq = (o >> 7) & 1, cc = (o >> 3) & 15, j = o & 7;
        int src = (t * 16 + cc) * 16 + qq * 8 + j;
        float2 v = *(const float2*)(W1 + src);
        sW1i[o2] = pack2bf(v.x, v.y);
    }
    if (tid < 8) ((int*)(smem + SZC))[tid] = 0;
    // ---- stage W2 in permuted frag order (v9-verified) ----
#pragma unroll
    for (int i = 0; i < 4; ++i) {
        int o2 = tid + i * 512;                 // b32 index 0..2047
        int chunk = o2 >> 8, rem = o2 & 255;
        int ln = rem >> 2, j2 = rem & 3;
        int qq = ln >> 4, cc = ln & 15;
        int t2 = chunk >> 2, s = chunk & 3;
        int src = (t2 * 16 + cc) * 128 + s * 32 + 4 * qq + j2;
        sW2i[o2] = pack2bf(W2[src], W2[src + 16]);
    }
    if (tid < 32) ((float*)(smem + SB2))[tid] = b2[tid];
    if (tid < 16) ((float*)(smem + SXT))[tid] = x_t[tid];
    // b1 replicated x4 so a single ds_read_b128 yields splat(b1[h]) for the C-seed
    if (tid < 128) {
        float v = b1[tid];
        ((float4*)(smem + SB1))[tid] = make_float4(v, v, v, v);
    }

    const int wave = tid >> 6, lane = tid & 63;
    const int c = lane & 15, q = lane >> 4;
    const int hh = (q & 1) * 8;                  // d-half this lane owns
    const int c4 = c * 4;

    const char* sW1f = smem + SW1;
    const int w1base = (q < 2) ? ((q * 16 + c) * 16) : (SZC - SW1);
    const int w1step = (q < 2) ? 512 : 0;
    const char* sW2f = smem + SW2 + lane * 16;   // + chunk*1024
    __bf16* hcw0 = (__bf16*)(smem + SHC + wave * 2560);
    __bf16* hcw1 = hcw0 + 640;
    const float* sB2f = (const float*)(smem + SB2);
    const float* sXTf = (const float*)(smem + SXT);
    const float* sB1r = (const float*)(smem + SB1);

    __syncthreads();

    const int blk_row = blockIdx.x * 512 + wave * 64;
    const f32x4 z4 = {0.f, 0.f, 0.f, 0.f};

    // p-invariant G2 bias seeds (layout matches D: reg r <-> n = half*16 + q*4+r)
    const f32x4 bq0 = *(const f32x4*)(sB2f + q * 4);
    const f32x4 bq1 = *(const f32x4*)(sB2f + 16 + q * 4);

    // ---- p=0 x load (prefetched inside loop thereafter) ----
    bf16x8 af[2];
#pragma unroll
    for (int t01 = 0; t01 < 2; ++t01) {
        f32x8 xv = load8(x_cur + (size_t)(blk_row + t01 * 16 + c) * 16 + hh);
        af[t01] = __builtin_convertvector(xv, bf16x8);
    }

#pragma unroll 1
    for (int p = 0; p < 2; ++p) {
        const int r0 = blk_row + p * 32;

        // ---- fused G1/G2, t01-interleaved; bias enters via MFMA C-operand ----
        f32x4 acc2[2][2];
        acc2[0][0] = bq0; acc2[0][1] = bq1; acc2[1][0] = bq0; acc2[1][1] = bq1;
#pragma unroll
        for (int s = 0; s < 4; ++s) {
            // splat(b1[h]) C-seeds: h = (2s)*16+c and (2s+1)*16+c (t01-invariant)
            f32x4 cba = *(const f32x4*)(sB1r + ((2 * s) * 16 + c) * 4);
            f32x4 cbb = *(const f32x4*)(sB1r + ((2 * s + 1) * 16 + c) * 4);
#pragma unroll
            for (int t01 = 0; t01 < 2; ++t01) {
                __bf16* hcw = t01 ? hcw1 : hcw0;
                bf16x8 w1a = *(const bf16x8*)(sW1f + w1base + (2 * s) * w1step);
                bf16x8 w1b = *(const bf16x8*)(sW1f + w1base + (2 * s + 1) * w1step);
                f32x4 a1a = __builtin_amdgcn_mfma_f32_16x16x32_bf16(af[t01], w1a, cba, 0, 0, 0);
                f32x4 a1b = __builtin_amdgcn_mfma_f32_16x16x32_bf16(af[t01], w1b, cbb, 0, 0, 0);
#pragma unroll
                for (int r = 0; r < 4; ++r) {
                    float va = fmaxf(a1a[r], 0.f);
                    float vb = fmaxf(a1b[r], 0.f);
                    *(int*)(hcw + (q * 4 + r) * 40 + 2 * c) = pack2bf(va, vb);
                }
            }
#pragma unroll
            for (int t01 = 0; t01 < 2; ++t01) {
                __bf16* hcw = t01 ? hcw1 : hcw0;
                bf16x8 hb = *(const bf16x8*)(hcw + c * 40 + q * 8);
                bf16x8 w20 = *(const bf16x8*)(sW2f + (0 * 4 + s) * 1024);
                bf16x8 w21 = *(const bf16x8*)(sW2f + (1 * 4 + s) * 1024);
                acc2[t01][0] = __builtin_amdgcn_mfma_f32_16x16x32_bf16(w20, hb, acc2[t01][0], 0, 0, 0);
                acc2[t01][1] = __builtin_amdgcn_mfma_f32_16x16x32_bf16(w21, hb, acc2[t01][1], 0, 0, 0);
            }
        }

        // ---- prefetch next-p x (issued here so HBM latency hides under SM+G3) ----
        bf16x8 afn0 = af[0], afn1 = af[1];
        if (p == 0) {
            f32x8 xv0 = load8(x_cur + (size_t)(blk_row + 32 + c) * 16 + hh);
            f32x8 xv1 = load8(x_cur + (size_t)(blk_row + 48 + c) * 16 + hh);
            afn0 = __builtin_convertvector(xv0, bf16x8);
            afn1 = __builtin_convertvector(xv1, bf16x8);
        }

        // ---- softmax, both t01 then single-pack ----
        int wq[8];
        {
            float e0[8], e1[8], sum0 = 0.f, sum1 = 0.f;
#pragma unroll
            for (int r = 0; r < 4; ++r) {
                e0[r]     = __expf(acc2[0][0][r]);
                e0[4 + r] = __expf(acc2[0][1][r]);
                e1[r]     = __expf(acc2[1][0][r]);
                e1[4 + r] = __expf(acc2[1][1][r]);
                sum0 += e0[r] + e0[4 + r];
                sum1 += e1[r] + e1[4 + r];
            }
            sum0 += __shfl_xor(sum0, 16, 64);
            sum0 += __shfl_xor(sum0, 32, 64);
            sum1 += __shfl_xor(sum1, 16, 64);
            sum1 += __shfl_xor(sum1, 32, 64);
            float inv0 = 1.0f / sum0;
            float inv1 = 1.0f / sum1;
#pragma unroll
            for (int i = 0; i < 8; ++i)
                wq[i] = pack2bf(e0[i] * inv0, e1[i] * inv1);
        }

        // ---- dif -> bf16 once per p; parity-masked B-operands ----
        // B-frag semantics: lane(c,q) supplies B[K=q*8+j][col=c]. K<16 (q<2) hits
        // A2's n=2kk half, K>=16 (q>=2) hits n=2kk+1. Lanes q>=2 hold the same
        // d-halves as q<2, so masking by q splits the systems cleanly.
        bf16x8 difbE[2], difbO[2];
        {
            f32x4 xta = *(const f32x4*)(sXTf + hh);
            f32x4 xtb = *(const f32x4*)(sXTf + hh + 4);
            f32x8 xtv = {xta[0], xta[1], xta[2], xta[3], xtb[0], xtb[1], xtb[2], xtb[3]};
            bf16x8 d0 = __builtin_convertvector(xtv - __builtin_convertvector(af[0], f32x8), bf16x8);
            bf16x8 d1 = __builtin_convertvector(xtv - __builtin_convertvector(af[1], f32x8), bf16x8);
            const bf16x8 zb = {};
            bool lowK = (q < 2);
            difbE[0] = lowK ? d0 : zb;
            difbE[1] = lowK ? d1 : zb;
            difbO[0] = lowK ? zb : d0;
            difbO[1] = lowK ? zb : d1;
        }

        // ---- G3: pure LDS->MFMA stream; gates applied to MFMA OUTPUTS ----
        f32x4 acc3[2];
        acc3[0] = z4; acc3[1] = z4;
#pragma unroll
        for (int kk = 0; kk < 16; ++kk) {
            const int lo = (kk >> 3) * 4 + 2 * (kk & 1);
            const int bpi = c4 + ((kk >> 1) & 3) * 64;
            int bpA = __builtin_amdgcn_ds_bpermute(bpi, wq[lo]);      // n = 2kk   (t01-packed)
            int bpB = __builtin_amdgcn_ds_bpermute(bpi, wq[lo + 1]);  // n = 2kk+1 (t01-packed)
            bf16x8 a2f = *(const bf16x8*)(smem + kk * 1024 + lane * 16);
            // MFMAs depend only on a2f + difb* (no gate dependency)
            f32x4 prE0 = __builtin_amdgcn_mfma_f32_16x16x32_bf16(a2f, difbE[0], z4, 0, 0, 0);
            f32x4 prO0 = __builtin_amdgcn_mfma_f32_16x16x32_bf16(a2f, difbO[0], z4, 0, 0, 0);
            f32x4 prE1 = __builtin_amdgcn_mfma_f32_16x16x32_bf16(a2f, difbE[1], z4, 0, 0, 0);
            f32x4 prO1 = __builtin_amdgcn_mfma_f32_16x16x32_bf16(a2f, difbO[1], z4, 0, 0, 0);
            float wA0 = __builtin_bit_cast(float, (unsigned)bpA << 16);
            float wA1 = __builtin_bit_cast(float, (unsigned)bpA & 0xffff0000u);
            float wB0 = __builtin_bit_cast(float, (unsigned)bpB << 16);
            float wB1 = __builtin_bit_cast(float, (unsigned)bpB & 0xffff0000u);
            acc3[0] += wA0 * prE0 + wB0 * prO0;
            acc3[1] += wA1 * prE1 + wB1 * prO1;
        }

        // ---- store: D[m=k_out=q*4+r][n=row=c] -> float4 per tile ----
#pragma unroll
        for (int t01 = 0; t01 < 2; ++t01) {
            float4 st = make_float4(acc3[t01][0], acc3[t01][1], acc3[t01][2], acc3[t01][3]);
            *(float4*)(out + (size_t)(r0 + t01 * 16 + c) * 16 + q * 4) = st;
        }

        af[0] = afn0;
        af[1] = afn1;
    }
}

extern "C" void kernel_launch(void* const* d_in, const int* in_sizes, int n_in,
                              void* d_out, int out_size, void* d_ws, size_t ws_size,
                              hipStream_t stream) {
    const float* x_cur = (const float*)d_in[0];
    const float* W1    = (const float*)d_in[1];
    const float* b1    = (const float*)d_in[2];
    const float* W2    = (const float*)d_in[3];
    const float* b2    = (const float*)d_in[4];
    const float* Bm    = (const float*)d_in[5];
    const float* Cm    = (const float*)d_in[6];
    const float* x_t   = (const float*)d_in[7];
    float* out = (float*)d_out;

    const int blocks = BATCH / 512;   // 1024 blocks x 512 rows, 3 blocks/CU resident
    andp_v18<<<blocks, 512, SMEM_BYTES, stream>>>(
        x_cur, W1, b1, W2, b2, Bm, Cm, x_t, out);
}

// Round 22
// 118.392 us; speedup vs baseline: 1.0363x; 1.0080x over previous
//
#include <hip/hip_runtime.h>

#define BATCH 524288
#define CHUNK_STRIDE (BATCH / 2)   // 262144 rows: block b owns rows of chunk0 and chunk1

typedef __bf16 bf16x8 __attribute__((ext_vector_type(8)));
typedef __bf16 bf16x2 __attribute__((ext_vector_type(2)));
typedef float f32x4 __attribute__((ext_vector_type(4)));
typedef float f32x8 __attribute__((ext_vector_type(8)));
typedef float f32x2 __attribute__((ext_vector_type(2)));
typedef int   i32x4 __attribute__((ext_vector_type(4)));

// LDS layout (all fragment reads are lane-consecutive 16B chunks = conflict-free):
//   sA2  @     0: 16384 B  A2, chunk(kk, lane)=kk*1024+lane*16
//   sW1f @ 16384:  4096 B  W1 frags; +32 B zero chunk @ 20480
//   sW2f @ 20512:  8192 B  W2 permuted frags (v9-verified)
//   sB2  @ 28704:   128 B  b2 f32 (f32x4 broadcast reads, seeds G2 C-operand)
//   sXT  @ 28832:    64 B  x_target f32
//   sB1r @ 28896:  2048 B  b1 replicated x4 (f32x4 splat reads, seeds G1 C-operand)
//   hcw  @ 30944 + wave*2560 + t01*1280: 16 rows x 40 bf16
//
// v19: fat blocks — fix the scheduling tail (v13-v18 post-mortem: duration
//      insensitive to occupancy caps/VALU/DS/MFMA counts; all pipes <50% busy;
//      v11 with perfect 2-blocks/CU packing measured 68% occupancy vs v13/v14's
//      ~30% — the 1024-blocks-over-3-slots grid runs a 3+1 ROUND STRUCTURE with
//      a full tail round at 1/3 residency). Fix: 512 blocks x 2 chunks each
//      (4-iteration p-loop, r0 = blk + (p>>1)*262144 + (p&1)*32) -> exactly
//      2 blocks/CU, all resident start-to-finish, zero tail; staging amortized
//      2x. Kernel body otherwise byte-identical to v14 (41.7us verified).
#define SW1 16384
#define SZC 20480
#define SW2 20512
#define SB2 28704
#define SXT 28832
#define SB1 28896
#define SHC 30944
#define NWAVES 8
#define SMEM_BYTES (30944 + NWAVES * 2560)   // 51424 B

__device__ __forceinline__ f32x8 load8(const float* __restrict__ p) {
    float4 a = *(const float4*)p;
    float4 b = *(const float4*)(p + 4);
    f32x8 v = {a.x, a.y, a.z, a.w, b.x, b.y, b.z, b.w};
    return v;
}

__device__ __forceinline__ int pack2bf(float a, float b) {
    f32x2 v = {a, b};
    bf16x2 p = __builtin_convertvector(v, bf16x2);
    return __builtin_bit_cast(int, p);
}

__global__ __launch_bounds__(512, 3) void andp_v19(
    const float* __restrict__ x_cur,
    const float* __restrict__ W1,
    const float* __restrict__ b1,
    const float* __restrict__ W2,
    const float* __restrict__ b2,
    const float* __restrict__ Bm,
    const float* __restrict__ Cm,
    const float* __restrict__ x_t,
    float* __restrict__ out)
{
    extern __shared__ char smem[];
    int* sA2i = (int*)smem;
    int* sW1i = (int*)(smem + SW1);
    int* sW2i = (int*)(smem + SW2);
    const int tid = threadIdx.x;

    // ---- stage A2 = Bm + Cm, lane-consecutive chunk order ----
#pragma unroll
    for (int i = 0; i < 8; ++i) {
        int o2 = tid + i * 512;                 // b32 index 0..4095
        int o  = o2 * 2;                        // elem (j even)
        int kk = o >> 9, qp = (o >> 7) & 3, k = (o >> 3) & 15, j = o & 7;
        int n = 2 * kk + (qp >> 1), d = (qp & 1) * 8 + j;
        int src = n * 256 + k * 16 + d;
        float2 bv = *(const float2*)(Bm + src);
        float2 cv = *(const float2*)(Cm + src);
        sA2i[o2] = pack2bf(bv.x + cv.x, bv.y + cv.y);
    }
    // ---- stage W1 frags, lane-consecutive chunk order; + zero chunk ----
#pragma unroll
    for (int i = 0; i < 2; ++i) {
        int o2 = tid + i * 512;                 // b32 index 0..1023
        int o  = o2 * 2;                        // elem (j even)
        int t = o >> 8, qq = (o >> 7) & 1, cc = (o >> 3) & 15, j = o & 7;
        int src = (t * 16 + cc) * 16 + qq * 8 + j;
        float2 v = *(const float2*)(W1 + src);
        sW1i[o2] = pack2bf(v.x, v.y);
    }
    if (tid < 8) ((int*)(smem + SZC))[tid] = 0;
    // ---- stage W2 in permuted frag order (v9-verified) ----
#pragma unroll
    for (int i = 0; i < 4; ++i) {
        int o2 = tid + i * 512;                 // b32 index 0..2047
        int chunk = o2 >> 8, rem = o2 & 255;
        int ln = rem >> 2, j2 = rem & 3;
        int qq = ln >> 4, cc = ln & 15;
        int t2 = chunk >> 2, s = chunk & 3;
        int src = (t2 * 16 + cc) * 128 + s * 32 + 4 * qq + j2;
        sW2i[o2] = pack2bf(W2[src], W2[src + 16]);
    }
    if (tid < 32) ((float*)(smem + SB2))[tid] = b2[tid];
    if (tid < 16) ((float*)(smem + SXT))[tid] = x_t[tid];
    // b1 replicated x4 so a single ds_read_b128 yields splat(b1[h]) for the C-seed
    if (tid < 128) {
        float v = b1[tid];
        ((float4*)(smem + SB1))[tid] = make_float4(v, v, v, v);
    }

    const int wave = tid >> 6, lane = tid & 63;
    const int c = lane & 15, q = lane >> 4;
    const int qh = q >> 1;                       // n parity for G3
    const int hh = (q & 1) * 8;                  // d-half this lane owns
    const int c4 = c * 4;

    const char* sW1f = smem + SW1;
    const int w1base = (q < 2) ? ((q * 16 + c) * 16) : (SZC - SW1);
    const int w1step = (q < 2) ? 512 : 0;
    const char* sW2f = smem + SW2 + lane * 16;   // + chunk*1024
    __bf16* hcw0 = (__bf16*)(smem + SHC + wave * 2560);
    __bf16* hcw1 = hcw0 + 640;
    const float* sB2f = (const float*)(smem + SB2);
    const float* sXTf = (const float*)(smem + SXT);
    const float* sB1r = (const float*)(smem + SB1);

    __syncthreads();

    const int blk_row = blockIdx.x * 512 + wave * 64;
    const f32x4 z4 = {0.f, 0.f, 0.f, 0.f};

    // p-invariant G2 bias seeds (layout matches D: reg r <-> n = half*16 + q*4+r)
    const f32x4 bq0 = *(const f32x4*)(sB2f + q * 4);
    const f32x4 bq1 = *(const f32x4*)(sB2f + 16 + q * 4);

    // ---- p=0 x load (prefetched inside loop thereafter) ----
    bf16x8 af[2];
#pragma unroll
    for (int t01 = 0; t01 < 2; ++t01) {
        f32x8 xv = load8(x_cur + (size_t)(blk_row + t01 * 16 + c) * 16 + hh);
        af[t01] = __builtin_convertvector(xv, bf16x8);
    }

    // 4 p-iterations: (p>>1) selects the chunk, (p&1) the 32-row half
#pragma unroll 1
    for (int p = 0; p < 4; ++p) {
        const int r0 = blk_row + (p >> 1) * CHUNK_STRIDE + (p & 1) * 32;

        // ---- fused G1/G2, t01-interleaved; bias enters via MFMA C-operand ----
        f32x4 acc2[2][2];
        acc2[0][0] = bq0; acc2[0][1] = bq1; acc2[1][0] = bq0; acc2[1][1] = bq1;
#pragma unroll
        for (int s = 0; s < 4; ++s) {
            // splat(b1[h]) C-seeds: h = (2s)*16+c and (2s+1)*16+c (t01-invariant)
            f32x4 cba = *(const f32x4*)(sB1r + ((2 * s) * 16 + c) * 4);
            f32x4 cbb = *(const f32x4*)(sB1r + ((2 * s + 1) * 16 + c) * 4);
#pragma unroll
            for (int t01 = 0; t01 < 2; ++t01) {
                __bf16* hcw = t01 ? hcw1 : hcw0;
                bf16x8 w1a = *(const bf16x8*)(sW1f + w1base + (2 * s) * w1step);
                bf16x8 w1b = *(const bf16x8*)(sW1f + w1base + (2 * s + 1) * w1step);
                f32x4 a1a = __builtin_amdgcn_mfma_f32_16x16x32_bf16(af[t01], w1a, cba, 0, 0, 0);
                f32x4 a1b = __builtin_amdgcn_mfma_f32_16x16x32_bf16(af[t01], w1b, cbb, 0, 0, 0);
#pragma unroll
                for (int r = 0; r < 4; ++r) {
                    float va = fmaxf(a1a[r], 0.f);
                    float vb = fmaxf(a1b[r], 0.f);
                    *(int*)(hcw + (q * 4 + r) * 40 + 2 * c) = pack2bf(va, vb);
                }
            }
#pragma unroll
            for (int t01 = 0; t01 < 2; ++t01) {
                __bf16* hcw = t01 ? hcw1 : hcw0;
                bf16x8 hb = *(const bf16x8*)(hcw + c * 40 + q * 8);
                bf16x8 w20 = *(const bf16x8*)(sW2f + (0 * 4 + s) * 1024);
                bf16x8 w21 = *(const bf16x8*)(sW2f + (1 * 4 + s) * 1024);
                acc2[t01][0] = __builtin_amdgcn_mfma_f32_16x16x32_bf16(w20, hb, acc2[t01][0], 0, 0, 0);
                acc2[t01][1] = __builtin_amdgcn_mfma_f32_16x16x32_bf16(w21, hb, acc2[t01][1], 0, 0, 0);
            }
        }

        // ---- prefetch next-p x (issued here so HBM latency hides under SM+G3) ----
        bf16x8 afn0 = af[0], afn1 = af[1];
        if (p < 3) {
            const int rn = blk_row + ((p + 1) >> 1) * CHUNK_STRIDE + ((p + 1) & 1) * 32;
            f32x8 xv0 = load8(x_cur + (size_t)(rn + c) * 16 + hh);
            f32x8 xv1 = load8(x_cur + (size_t)(rn + 16 + c) * 16 + hh);
            afn0 = __builtin_convertvector(xv0, bf16x8);
            afn1 = __builtin_convertvector(xv1, bf16x8);
        }

        // ---- softmax, both t01 then single-pack ----
        int wq[8];
        {
            float e0[8], e1[8], sum0 = 0.f, sum1 = 0.f;
#pragma unroll
            for (int r = 0; r < 4; ++r) {
                e0[r]     = __expf(acc2[0][0][r]);
                e0[4 + r] = __expf(acc2[0][1][r]);
                e1[r]     = __expf(acc2[1][0][r]);
                e1[4 + r] = __expf(acc2[1][1][r]);
                sum0 += e0[r] + e0[4 + r];
                sum1 += e1[r] + e1[4 + r];
            }
            sum0 += __shfl_xor(sum0, 16, 64);
            sum0 += __shfl_xor(sum0, 32, 64);
            sum1 += __shfl_xor(sum1, 16, 64);
            sum1 += __shfl_xor(sum1, 32, 64);
            float inv0 = 1.0f / sum0;
            float inv1 = 1.0f / sum1;
#pragma unroll
            for (int i = 0; i < 8; ++i)
                wq[i] = pack2bf(e0[i] * inv0, e1[i] * inv1);
        }

        // ---- reconstruct dif from af (bf16 x) + LDS x_target ----
        f32x8 dif[2];
        {
            f32x4 xta = *(const f32x4*)(sXTf + hh);
            f32x4 xtb = *(const f32x4*)(sXTf + hh + 4);
            f32x8 xtv = {xta[0], xta[1], xta[2], xta[3], xtb[0], xtb[1], xtb[2], xtb[3]};
            dif[0] = xtv - __builtin_convertvector(af[0], f32x8);
            dif[1] = xtv - __builtin_convertvector(af[1], f32x8);
        }

        // ---- G3 (v14 interleaved form; f32x2-structured scaling) ----
        f32x4 acc3[2];
        acc3[0] = z4; acc3[1] = z4;
#pragma unroll
        for (int kk = 0; kk < 16; ++kk) {
            const int lo = (kk >> 3) * 4 + 2 * (kk & 1);
            const int bpi = c4 + ((kk >> 1) & 3) * 64;
            int bpA = __builtin_amdgcn_ds_bpermute(bpi, wq[lo]);      // n = 2kk
            int bpB = __builtin_amdgcn_ds_bpermute(bpi, wq[lo + 1]);  // n = 2kk+1
            int sel = qh ? bpB : bpA;                                  // n = 2kk+qh
            float w0 = __builtin_bit_cast(float, (unsigned)sel << 16);
            float w1 = __builtin_bit_cast(float, (unsigned)sel & 0xffff0000u);
            f32x2 w0p = {w0, w0}, w1p = {w1, w1};
            i32x4 g0i, g1i;
#pragma unroll
            for (int jj = 0; jj < 4; ++jj) {
                f32x2 d0 = {dif[0][2 * jj], dif[0][2 * jj + 1]};
                f32x2 d1 = {dif[1][2 * jj], dif[1][2 * jj + 1]};
                f32x2 p0 = d0 * w0p;
                f32x2 p1 = d1 * w1p;
                g0i[jj] = pack2bf(p0[0], p0[1]);
                g1i[jj] = pack2bf(p1[0], p1[1]);
            }
            bf16x8 a2f = *(const bf16x8*)(smem + kk * 1024 + lane * 16);
            bf16x8 g0 = __builtin_bit_cast(bf16x8, g0i);
            bf16x8 g1 = __builtin_bit_cast(bf16x8, g1i);
            acc3[0] = __builtin_amdgcn_mfma_f32_16x16x32_bf16(a2f, g0, acc3[0], 0, 0, 0);
            acc3[1] = __builtin_amdgcn_mfma_f32_16x16x32_bf16(a2f, g1, acc3[1], 0, 0, 0);
        }

        // ---- store: D[m=k_out=q*4+r][n=row=c] -> float4 per tile ----
#pragma unroll
        for (int t01 = 0; t01 < 2; ++t01) {
            float4 st = make_float4(acc3[t01][0], acc3[t01][1], acc3[t01][2], acc3[t01][3]);
            *(float4*)(out + (size_t)(r0 + t01 * 16 + c) * 16 + q * 4) = st;
        }

        af[0] = afn0;
        af[1] = afn1;
    }
}

extern "C" void kernel_launch(void* const* d_in, const int* in_sizes, int n_in,
                              void* d_out, int out_size, void* d_ws, size_t ws_size,
                              hipStream_t stream) {
    const float* x_cur = (const float*)d_in[0];
    const float* W1    = (const float*)d_in[1];
    const float* b1    = (const float*)d_in[2];
    const float* W2    = (const float*)d_in[3];
    const float* b2    = (const float*)d_in[4];
    const float* Bm    = (const float*)d_in[5];
    const float* Cm    = (const float*)d_in[6];
    const float* x_t   = (const float*)d_in[7];
    float* out = (float*)d_out;

    // 512 fat blocks x 2 chunks: exactly 2 blocks/CU, all resident, zero tail
    const int blocks = BATCH / 1024;
    andp_v19<<<blocks, 512, SMEM_BYTES, stream>>>(
        x_cur, W1, b1, W2, b2, Bm, Cm, x_t, out);
}